// Round 1
// baseline (7614.030 us; speedup 1.0000x reference)
//
#include <hip/hip_runtime.h>
#include <math.h>

#define DIMM 512
#define SPAT 784
#define BM 64
#define BN 64
#define BK 16
#define MATF ((size_t)DIMM * DIMM)   // 262144 floats per matrix

// ---------------------------------------------------------------------------
// Batched C[bz] = alpha * (A[bz] @ B[bz]) + diag * I      (all 512x512 row-major)
// grid: (64 tiles = 8x8, nbatch), block 256
// ---------------------------------------------------------------------------
__global__ __launch_bounds__(256) void gemm_nn(
    const float* __restrict__ Ab, const float* __restrict__ Bb, float* __restrict__ Cb,
    float alpha, float diag)
{
    const int bz = blockIdx.y;
    const float* A = Ab + bz * MATF;
    const float* B = Bb + bz * MATF;
    float* C = Cb + bz * MATF;

    const int bx = blockIdx.x & 7;
    const int by = blockIdx.x >> 3;
    const int m0 = by * BM, n0 = bx * BN;

    __shared__ __align__(16) float As[BK][BM];   // [k][m]
    __shared__ __align__(16) float Bs[BK][BN];   // [k][n]

    const int t  = threadIdx.x;
    const int lr = t >> 2, lc = (t & 3) << 2;     // A-tile load: row, col4
    const int br = t >> 4, bc = (t & 15) << 2;    // B-tile load: row, col4
    const int tx = t & 15, ty = t >> 4;           // compute mapping

    float acc[4][4] = {};

    for (int k0 = 0; k0 < DIMM; k0 += BK) {
        float4 a4 = *(const float4*)(A + (size_t)(m0 + lr) * DIMM + k0 + lc);
        float4 b4 = *(const float4*)(B + (size_t)(k0 + br) * DIMM + n0 + bc);
        As[lc + 0][lr] = a4.x; As[lc + 1][lr] = a4.y;
        As[lc + 2][lr] = a4.z; As[lc + 3][lr] = a4.w;
        *(float4*)&Bs[br][bc] = b4;
        __syncthreads();
#pragma unroll
        for (int kk = 0; kk < BK; ++kk) {
            float4 av = *(const float4*)&As[kk][ty << 2];
            float4 bv = *(const float4*)&Bs[kk][tx << 2];
            acc[0][0] += av.x * bv.x; acc[0][1] += av.x * bv.y; acc[0][2] += av.x * bv.z; acc[0][3] += av.x * bv.w;
            acc[1][0] += av.y * bv.x; acc[1][1] += av.y * bv.y; acc[1][2] += av.y * bv.z; acc[1][3] += av.y * bv.w;
            acc[2][0] += av.z * bv.x; acc[2][1] += av.z * bv.y; acc[2][2] += av.z * bv.z; acc[2][3] += av.z * bv.w;
            acc[3][0] += av.w * bv.x; acc[3][1] += av.w * bv.y; acc[3][2] += av.w * bv.z; acc[3][3] += av.w * bv.w;
        }
        __syncthreads();
    }

#pragma unroll
    for (int i = 0; i < 4; ++i) {
        const int m = m0 + (ty << 2) + i;
        const int nb = n0 + (tx << 2);
        float4 o;
        o.x = alpha * acc[i][0] + ((m == nb + 0) ? diag : 0.f);
        o.y = alpha * acc[i][1] + ((m == nb + 1) ? diag : 0.f);
        o.z = alpha * acc[i][2] + ((m == nb + 2) ? diag : 0.f);
        o.w = alpha * acc[i][3] + ((m == nb + 3) ? diag : 0.f);
        *(float4*)(C + (size_t)m * DIMM + nb) = o;
    }
}

// ---------------------------------------------------------------------------
// Batched Gram: C[bz] = alpha * X[bz] @ X[bz]^T, X is 512x784 row-major
// ---------------------------------------------------------------------------
__global__ __launch_bounds__(256) void gram_nt(
    const float* __restrict__ Xb, float* __restrict__ Cb, float alpha)
{
    const int bz = blockIdx.y;
    const float* A = Xb + (size_t)bz * DIMM * SPAT;
    float* C = Cb + bz * MATF;

    const int bx = blockIdx.x & 7;
    const int by = blockIdx.x >> 3;
    const int m0 = by * BM, n0 = bx * BN;

    __shared__ __align__(16) float As[BK][BM];
    __shared__ __align__(16) float Bs[BK][BN];

    const int t  = threadIdx.x;
    const int lr = t >> 2, lc = (t & 3) << 2;
    const int tx = t & 15, ty = t >> 4;

    float acc[4][4] = {};

    for (int k0 = 0; k0 < SPAT; k0 += BK) {
        float4 a4 = *(const float4*)(A + (size_t)(m0 + lr) * SPAT + k0 + lc);
        float4 b4 = *(const float4*)(A + (size_t)(n0 + lr) * SPAT + k0 + lc);
        As[lc + 0][lr] = a4.x; As[lc + 1][lr] = a4.y;
        As[lc + 2][lr] = a4.z; As[lc + 3][lr] = a4.w;
        Bs[lc + 0][lr] = b4.x; Bs[lc + 1][lr] = b4.y;
        Bs[lc + 2][lr] = b4.z; Bs[lc + 3][lr] = b4.w;
        __syncthreads();
#pragma unroll
        for (int kk = 0; kk < BK; ++kk) {
            float4 av = *(const float4*)&As[kk][ty << 2];
            float4 bv = *(const float4*)&Bs[kk][tx << 2];
            acc[0][0] += av.x * bv.x; acc[0][1] += av.x * bv.y; acc[0][2] += av.x * bv.z; acc[0][3] += av.x * bv.w;
            acc[1][0] += av.y * bv.x; acc[1][1] += av.y * bv.y; acc[1][2] += av.y * bv.z; acc[1][3] += av.y * bv.w;
            acc[2][0] += av.z * bv.x; acc[2][1] += av.z * bv.y; acc[2][2] += av.z * bv.z; acc[2][3] += av.z * bv.w;
            acc[3][0] += av.w * bv.x; acc[3][1] += av.w * bv.y; acc[3][2] += av.w * bv.z; acc[3][3] += av.w * bv.w;
        }
        __syncthreads();
    }

#pragma unroll
    for (int i = 0; i < 4; ++i) {
        const int m = m0 + (ty << 2) + i;
        const int nb = n0 + (tx << 2);
        float4 o;
        o.x = alpha * acc[i][0]; o.y = alpha * acc[i][1];
        o.z = alpha * acc[i][2]; o.w = alpha * acc[i][3];
        *(float4*)(C + (size_t)m * DIMM + nb) = o;
    }
}

// ---------------------------------------------------------------------------
// Frobenius norm per batch: out[ob+blockIdx.x] = sqrt(sum(P[b]^2))
// ---------------------------------------------------------------------------
__global__ __launch_bounds__(256) void frob_norm(
    const float* __restrict__ P, float* __restrict__ out, int ob)
{
    const float* p = P + (size_t)blockIdx.x * MATF;
    float s = 0.f;
    for (int i = threadIdx.x * 4; i < DIMM * DIMM; i += 1024) {
        float4 v = *(const float4*)(p + i);
        s += v.x * v.x + v.y * v.y + v.z * v.z + v.w * v.w;
    }
    __shared__ float red[256];
    red[threadIdx.x] = s;
    __syncthreads();
    for (int w = 128; w > 0; w >>= 1) {
        if (threadIdx.x < w) red[threadIdx.x] += red[threadIdx.x + w];
        __syncthreads();
    }
    if (threadIdx.x == 0) out[ob + blockIdx.x] = sqrtf(red[0]);
}

// ---------------------------------------------------------------------------
// Y *= 1/norm (in place), Z = I.    grid: (64, nbatch); 4096 elems per block.x
// ---------------------------------------------------------------------------
__global__ __launch_bounds__(256) void init_yz(
    float* __restrict__ Y, float* __restrict__ Z, const float* __restrict__ norm, int b0)
{
    const int bl = blockIdx.y;
    const float rn = 1.0f / norm[b0 + bl];
    const int base = blockIdx.x * 4096;
    float* y = Y + (size_t)bl * MATF + base;
    float* z = Z + (size_t)bl * MATF + base;
    for (int i = threadIdx.x * 4; i < 4096; i += 1024) {
        float4 v = *(const float4*)(y + i);
        v.x *= rn; v.y *= rn; v.z *= rn; v.w *= rn;
        *(float4*)(y + i) = v;
        const int e = base + i;
        const int row = e >> 9;
        const int col = e & 511;
        float4 zi;
        zi.x = (col + 0 == row) ? 1.f : 0.f;
        zi.y = (col + 1 == row) ? 1.f : 0.f;
        zi.z = (col + 2 == row) ? 1.f : 0.f;
        zi.w = (col + 3 == row) ? 1.f : 0.f;
        *(float4*)(z + i) = zi;
    }
}

// ---------------------------------------------------------------------------
// v = sign(y*s) * sqrt(|y*s| + 1e-5), s = sqrt(norm[gb]).  Writes V at global
// batch offset. grid: (64, nbatch)
// ---------------------------------------------------------------------------
__device__ __forceinline__ float sgn_sqrt(float t)
{
    float r = sqrtf(fabsf(t) + 1e-5f);
    return t > 0.f ? r : (t < 0.f ? -r : 0.f);
}

__global__ __launch_bounds__(256) void signed_sqrt_k(
    const float* __restrict__ Y, float* __restrict__ V,
    const float* __restrict__ norm, int b0)
{
    const int bl = blockIdx.y;
    const int gb = b0 + bl;
    const float s = sqrtf(norm[gb]);
    const float* y = Y + (size_t)bl * MATF + blockIdx.x * 4096;
    float* v = V + (size_t)gb * MATF + blockIdx.x * 4096;
    for (int i = threadIdx.x * 4; i < 4096; i += 1024) {
        float4 a = *(const float4*)(y + i);
        float4 r;
        r.x = sgn_sqrt(a.x * s);
        r.y = sgn_sqrt(a.y * s);
        r.z = sgn_sqrt(a.z * s);
        r.w = sgn_sqrt(a.w * s);
        *(float4*)(v + i) = r;
    }
}

// ---------------------------------------------------------------------------
// FC partial GEMM: part[sp][nt][m][n] = sum_{k in split sp} V[m][k]*W[n0+n][k]
// V: 64 x 262144, W: 200 x 262144 (rows used transposed). grid (4, 128).
// ---------------------------------------------------------------------------
__global__ __launch_bounds__(256) void fc_partial(
    const float* __restrict__ V, const float* __restrict__ Wfc, float* __restrict__ part)
{
    const int nt = blockIdx.x;          // n-tile 0..3 (cols 64*nt .. +63, guard >=200)
    const int sp = blockIdx.y;          // k-split 0..127
    const int n0 = nt * BN;
    const size_t K = MATF;              // 262144
    const int kbase = sp * 2048;

    __shared__ __align__(16) float As[BK][BM];
    __shared__ __align__(16) float Bs[BK][BN];

    const int t  = threadIdx.x;
    const int lr = t >> 2, lc = (t & 3) << 2;
    const int tx = t & 15, ty = t >> 4;

    const int wrow = n0 + lr;
    const bool wvalid = wrow < 200;
    const float* wp = Wfc + (size_t)wrow * K;

    float acc[4][4] = {};

    for (int k0 = kbase; k0 < kbase + 2048; k0 += BK) {
        float4 a4 = *(const float4*)(V + (size_t)lr * K + k0 + lc);
        float4 w4 = make_float4(0.f, 0.f, 0.f, 0.f);
        if (wvalid) w4 = *(const float4*)(wp + k0 + lc);
        As[lc + 0][lr] = a4.x; As[lc + 1][lr] = a4.y;
        As[lc + 2][lr] = a4.z; As[lc + 3][lr] = a4.w;
        Bs[lc + 0][lr] = w4.x; Bs[lc + 1][lr] = w4.y;
        Bs[lc + 2][lr] = w4.z; Bs[lc + 3][lr] = w4.w;
        __syncthreads();
#pragma unroll
        for (int kk = 0; kk < BK; ++kk) {
            float4 av = *(const float4*)&As[kk][ty << 2];
            float4 bv = *(const float4*)&Bs[kk][tx << 2];
            acc[0][0] += av.x * bv.x; acc[0][1] += av.x * bv.y; acc[0][2] += av.x * bv.z; acc[0][3] += av.x * bv.w;
            acc[1][0] += av.y * bv.x; acc[1][1] += av.y * bv.y; acc[1][2] += av.y * bv.z; acc[1][3] += av.y * bv.w;
            acc[2][0] += av.z * bv.x; acc[2][1] += av.z * bv.y; acc[2][2] += av.z * bv.z; acc[2][3] += av.z * bv.w;
            acc[3][0] += av.w * bv.x; acc[3][1] += av.w * bv.y; acc[3][2] += av.w * bv.z; acc[3][3] += av.w * bv.w;
        }
        __syncthreads();
    }

    float* pbase = part + (((size_t)sp * 4 + nt) * 64) * 64;
#pragma unroll
    for (int i = 0; i < 4; ++i) {
        const int m = (ty << 2) + i;
        float4 o;
        o.x = acc[i][0]; o.y = acc[i][1]; o.z = acc[i][2]; o.w = acc[i][3];
        *(float4*)(pbase + (size_t)m * 64 + (tx << 2)) = o;
    }
}

// ---------------------------------------------------------------------------
// Final reduce: out[b][o] = (sum_sp part[sp][o/64][b][o%64]) / max(n2[b],1e-12) + bias[o]
// ---------------------------------------------------------------------------
__global__ __launch_bounds__(256) void fc_reduce(
    const float* __restrict__ part, const float* __restrict__ n2,
    const float* __restrict__ bias, float* __restrict__ out)
{
    const int p = blockIdx.x * 256 + threadIdx.x;
    if (p >= 64 * 200) return;
    const int b = p / 200, o = p % 200;
    const int nt = o >> 6, n = o & 63;
    float s = 0.f;
    for (int c = 0; c < 128; ++c)
        s += part[(((size_t)c * 4 + nt) * 64 + b) * 64 + n];
    const float nb = fmaxf(n2[b], 1e-12f);
    out[p] = s / nb + bias[o];
}

// ---------------------------------------------------------------------------
extern "C" void kernel_launch(void* const* d_in, const int* in_sizes, int n_in,
                              void* d_out, int out_size, void* d_ws, size_t ws_size,
                              hipStream_t stream)
{
    const float* X    = (const float*)d_in[0];   // (64, 512, 784)
    const float* Wfc  = (const float*)d_in[1];   // (200, 262144)
    const float* bias = (const float*)d_in[2];   // (200,)
    float* out = (float*)d_out;                  // (64, 200)

    // ws layout: [norm 64][norm2 64][part 128*4*64*64][buffers...]
    float* norm   = (float*)d_ws;
    float* norm2  = norm + 64;
    float* part   = norm2 + 64;
    float* region = part + (size_t)128 * 4 * 64 * 64;
    const size_t auxB = (size_t)((char*)region - (char*)d_ws);

    int NB = 64;
    bool sep_v = false;
    if (ws_size < auxB + 4ull * 64 * MATF * sizeof(float)) {
        sep_v = true;
        for (NB = 32; NB > 1; NB >>= 1)
            if (ws_size >= auxB + (64ull + 4ull * NB) * MATF * sizeof(float)) break;
    }

    float *B0, *B1, *B2, *B3, *vbuf;
    if (!sep_v) {
        B0 = region; B1 = B0 + 64 * MATF; B2 = B1 + 64 * MATF; B3 = B2 + 64 * MATF;
        vbuf = nullptr;  // assigned after rotation (a free buffer)
    } else {
        vbuf = region;
        B0 = vbuf + 64 * MATF;
        B1 = B0 + (size_t)NB * MATF;
        B2 = B1 + (size_t)NB * MATF;
        B3 = B2 + (size_t)NB * MATF;
    }

    for (int b0 = 0; b0 < 64; b0 += NB) {
        const int nb = (64 - b0 < NB) ? (64 - b0) : NB;
        const float* Xc = X + (size_t)b0 * DIMM * SPAT;
        float *y = B0, *z = B1, *f0 = B2, *f1 = B3;

        // A = X X^T / 784  -> y
        gram_nt<<<dim3(64, nb), 256, 0, stream>>>(Xc, y, 1.0f / (float)SPAT);
        // norm_A
        frob_norm<<<nb, 256, 0, stream>>>(y, norm, b0);
        // Y = A/norm, Z = I
        init_yz<<<dim3(64, nb), 256, 0, stream>>>(y, z, norm, b0);

        for (int it = 0; it < 10; ++it) {
            // T = 1.5 I - 0.5 Z@Y
            gemm_nn<<<dim3(64, nb), 256, 0, stream>>>(z, y, f0, -0.5f, 1.5f);
            // Ynew = Y @ T
            gemm_nn<<<dim3(64, nb), 256, 0, stream>>>(y, f0, f1, 1.0f, 0.0f);
            if (it < 9) {
                // Znew = T @ Z  (into old y slot)
                gemm_nn<<<dim3(64, nb), 256, 0, stream>>>(f0, z, y, 1.0f, 0.0f);
                float* tmp = y; y = f1; f1 = z; z = tmp;
            } else {
                y = f1;  // final Y; f0/z/old-y free
            }
        }

        float* vdst = sep_v ? vbuf : f0;   // f0 != y after rotation
        signed_sqrt_k<<<dim3(64, nb), 256, 0, stream>>>(y, vdst, norm, b0);
        if (!sep_v) vbuf = vdst;
    }

    // n2[b] = ||v_b||_2
    frob_norm<<<64, 256, 0, stream>>>(vbuf, norm2, 0);
    // partial FC gemm + reduce with normalization and bias
    fc_partial<<<dim3(4, 128), 256, 0, stream>>>(vbuf, Wfc, part);
    fc_reduce<<<50, 256, 0, stream>>>(part, norm2, bias, out);
}

// Round 2
// 3069.795 us; speedup vs baseline: 2.4803x; 2.4803x over previous
//
#include <hip/hip_runtime.h>
#include <math.h>
#include <stdint.h>

#define DIMM 512
#define SPAT 784
#define KPAD 800
#define MATF ((size_t)DIMM * DIMM)       // 262144
#define PLANE 262144                     // hi -> lo plane offset (ushorts) for 512x512
#define SLOT_USH (2 * 262144)            // pair slot per batch (ushorts) = 1 MiB
#define XPLANE (512 * 800)
#define XSLOT (2 * 512 * 800)

typedef __attribute__((ext_vector_type(8))) short short8v;
typedef __attribute__((ext_vector_type(8))) unsigned short ushort8v;
typedef __attribute__((ext_vector_type(4))) float f32x4;

__device__ __forceinline__ unsigned short bf16_rne(float f) {
    unsigned u = __builtin_bit_cast(unsigned, f);
    u += 0x7FFFu + ((u >> 16) & 1u);
    return (unsigned short)(u >> 16);
}
__device__ __forceinline__ float bf16_to_f(unsigned short h) {
    unsigned u = ((unsigned)h) << 16;
    return __builtin_bit_cast(float, u);
}

// ---------------------------------------------------------------------------
// Pair-plane batched GEMM:  acc = A_pair @ B_pair^T(rows-as-cols)
//   EP==0: C_pair = alpha * acc                       (Gram: B rows = X rows)
//   EP==1: C_pair = 1.5*A - 0.5*acc                   (NS: C = A @ T(M), B = M)
// hi/lo split MFMA: acc = Ah*Bh + Ah*Bl + Al*Bh  (lo*lo dropped, ~2^-18)
// grid (16 tiles, batch, nz), block 256 (4 waves, 2x2, 64x64 out each)
// ---------------------------------------------------------------------------
template<int EP>
__global__ __launch_bounds__(256) void gemm_pair(
    const unsigned short* __restrict__ A0, const unsigned short* __restrict__ A1,
    const unsigned short* __restrict__ Bb,
    unsigned short* __restrict__ C0, unsigned short* __restrict__ C1,
    int lda, long aslot, int aplane,
    int ldb, long bslot, int bplane,
    int K, float alpha)
{
    __shared__ unsigned short sm[4 * 128 * 40];   // 4 planes, rows padded to 80B
    const int SM_AH = 0, SM_AL = 5120, SM_BH = 10240, SM_BL = 15360;

    const int bz = blockIdx.y;
    const int z  = blockIdx.z;
    const unsigned short* A  = (z ? A1 : A0) + (size_t)bz * aslot;
    const unsigned short* Bp = Bb + (size_t)bz * bslot;
    unsigned short* C = (z ? C1 : C0) + (size_t)bz * SLOT_USH;

    const int m0 = (blockIdx.x >> 2) * 128;
    const int n0 = (blockIdx.x & 3) * 128;

    const int t = threadIdx.x;
    const int l = t & 63;
    const int w = t >> 6;
    const int wr = w >> 1, wc = w & 1;
    const int lr = l & 15, lc16 = (l >> 4) * 8;   // frag read: ushort offsets

    // staging: thread covers row sr (0..127), column-half sh (16 ushorts)
    const int sr = t >> 1, sh = t & 1;
    const unsigned short* pA = A  + (size_t)(m0 + sr) * lda + sh * 16;
    const unsigned short* pB = Bp + (size_t)(n0 + sr) * ldb + sh * 16;
    unsigned short* dAh = &sm[SM_AH + sr * 40 + sh * 16];
    unsigned short* dAl = &sm[SM_AL + sr * 40 + sh * 16];
    unsigned short* dBh = &sm[SM_BH + sr * 40 + sh * 16];
    unsigned short* dBl = &sm[SM_BL + sr * 40 + sh * 16];

    f32x4 acc[4][4] = {};

    ushort8v a0, a1, a2, a3, b0, b1, b2, b3;
#define LOADALL(OFF) do { \
    a0 = *(const ushort8v*)(pA + (OFF));              a1 = *(const ushort8v*)(pA + (OFF) + 8); \
    a2 = *(const ushort8v*)(pA + aplane + (OFF));     a3 = *(const ushort8v*)(pA + aplane + (OFF) + 8); \
    b0 = *(const ushort8v*)(pB + (OFF));              b1 = *(const ushort8v*)(pB + (OFF) + 8); \
    b2 = *(const ushort8v*)(pB + bplane + (OFF));     b3 = *(const ushort8v*)(pB + bplane + (OFF) + 8); \
  } while (0)

    LOADALL(0);
    const int nsteps = K >> 5;
    for (int s = 0; s < nsteps; ++s) {
        __syncthreads();
        *(ushort8v*)(dAh) = a0; *(ushort8v*)(dAh + 8) = a1;
        *(ushort8v*)(dAl) = a2; *(ushort8v*)(dAl + 8) = a3;
        *(ushort8v*)(dBh) = b0; *(ushort8v*)(dBh + 8) = b1;
        *(ushort8v*)(dBl) = b2; *(ushort8v*)(dBl + 8) = b3;
        __syncthreads();
        if (s + 1 < nsteps) LOADALL((s + 1) * 32);

        short8v ah[4], al[4], bh[4], bl[4];
#pragma unroll
        for (int f = 0; f < 4; ++f) {
            const int ra = (wr * 64 + f * 16 + lr) * 40 + lc16;
            const int rb = (wc * 64 + f * 16 + lr) * 40 + lc16;
            ah[f] = *(const short8v*)(&sm[SM_AH + ra]);
            al[f] = *(const short8v*)(&sm[SM_AL + ra]);
            bh[f] = *(const short8v*)(&sm[SM_BH + rb]);
            bl[f] = *(const short8v*)(&sm[SM_BL + rb]);
        }
#pragma unroll
        for (int fm = 0; fm < 4; ++fm)
#pragma unroll
            for (int fn = 0; fn < 4; ++fn) {
                acc[fm][fn] = __builtin_amdgcn_mfma_f32_16x16x32_bf16(ah[fm], bh[fn], acc[fm][fn], 0, 0, 0);
                acc[fm][fn] = __builtin_amdgcn_mfma_f32_16x16x32_bf16(ah[fm], bl[fn], acc[fm][fn], 0, 0, 0);
                acc[fm][fn] = __builtin_amdgcn_mfma_f32_16x16x32_bf16(al[fm], bh[fn], acc[fm][fn], 0, 0, 0);
            }
    }
#undef LOADALL

    // epilogue: C/D layout col = lane&15, row = (lane>>4)*4 + reg  [m89-verified]
#pragma unroll
    for (int fm = 0; fm < 4; ++fm) {
#pragma unroll
        for (int j = 0; j < 4; ++j) {
            const int row = m0 + wr * 64 + fm * 16 + (l >> 4) * 4 + j;
            const unsigned short* arow = A + (size_t)row * lda;
            const size_t crow = (size_t)row * 512;
#pragma unroll
            for (int fn = 0; fn < 4; ++fn) {
                const int col = n0 + wc * 64 + fn * 16 + lr;
                float v = acc[fm][fn][j];
                if (EP == 0) {
                    v *= alpha;
                } else {
                    float pv = bf16_to_f(arow[col]) + bf16_to_f(arow[aplane + col]);
                    v = 1.5f * pv - 0.5f * v;
                }
                unsigned short hh = bf16_rne(v);
                C[crow + col] = hh;
                C[crow + col + PLANE] = bf16_rne(v - bf16_to_f(hh));
            }
        }
    }
}

// ---------------------------------------------------------------------------
// X (64,512,784) fp32 -> hi/lo bf16 planes, K padded to 800 with zeros
// ---------------------------------------------------------------------------
__global__ __launch_bounds__(256) void xconv(const float* __restrict__ X,
                                             unsigned short* __restrict__ XHL)
{
    const int total = 64 * 512 * 200;   // groups of 4 cols (padded width 800)
    for (int idx = blockIdx.x * 256 + threadIdx.x; idx < total; idx += gridDim.x * 256) {
        const int c4 = (idx % 200) * 4;
        const int rb = idx / 200;       // b*512 + r
        const int b = rb >> 9, r = rb & 511;
        unsigned short* dst = XHL + (size_t)b * XSLOT + (size_t)r * 800 + c4;
        ushort4 hv, lv;
        if (c4 < 784) {
            float4 x = *(const float4*)(X + (size_t)rb * 784 + c4);
            unsigned short h0 = bf16_rne(x.x), h1 = bf16_rne(x.y),
                           h2 = bf16_rne(x.z), h3 = bf16_rne(x.w);
            hv.x = h0; hv.y = h1; hv.z = h2; hv.w = h3;
            lv.x = bf16_rne(x.x - bf16_to_f(h0));
            lv.y = bf16_rne(x.y - bf16_to_f(h1));
            lv.z = bf16_rne(x.z - bf16_to_f(h2));
            lv.w = bf16_rne(x.w - bf16_to_f(h3));
        } else {
            hv.x = hv.y = hv.z = hv.w = 0;
            lv.x = lv.y = lv.z = lv.w = 0;
        }
        *(ushort4*)dst = hv;
        *(ushort4*)(dst + XPLANE) = lv;
    }
}

// ---------------------------------------------------------------------------
// Frobenius norm of pair-plane matrix per batch
// ---------------------------------------------------------------------------
__global__ __launch_bounds__(256) void frob_pair(const unsigned short* __restrict__ P,
                                                 float* __restrict__ out)
{
    const unsigned short* p = P + (size_t)blockIdx.x * SLOT_USH;
    float s = 0.f;
    for (int i = threadIdx.x * 8; i < 262144; i += 2048) {
        ushort8v h = *(const ushort8v*)(p + i);
        ushort8v lo = *(const ushort8v*)(p + i + PLANE);
#pragma unroll
        for (int j = 0; j < 8; ++j) {
            float v = bf16_to_f(h[j]) + bf16_to_f(lo[j]);
            s += v * v;
        }
    }
    __shared__ float red[256];
    red[threadIdx.x] = s;
    __syncthreads();
    for (int wd = 128; wd > 0; wd >>= 1) {
        if (threadIdx.x < wd) red[threadIdx.x] += red[threadIdx.x + wd];
        __syncthreads();
    }
    if (threadIdx.x == 0) out[blockIdx.x] = sqrtf(red[0]);
}

// ---------------------------------------------------------------------------
// Y0_pair = A_pair / norm[b]
// ---------------------------------------------------------------------------
__global__ __launch_bounds__(256) void init_pair(const unsigned short* __restrict__ A,
                                                 unsigned short* __restrict__ Y,
                                                 const float* __restrict__ norm)
{
    const int total = 64 * 32768;      // groups of 8
    for (int g = blockIdx.x * 256 + threadIdx.x; g < total; g += gridDim.x * 256) {
        const int b = g >> 15;
        const int off = (g & 32767) * 8;
        const float rn = 1.0f / norm[b];
        const unsigned short* ah = A + (size_t)b * SLOT_USH + off;
        ushort8v h = *(const ushort8v*)ah;
        ushort8v lo = *(const ushort8v*)(ah + PLANE);
        ushort8v oh, ol;
#pragma unroll
        for (int j = 0; j < 8; ++j) {
            float v = (bf16_to_f(h[j]) + bf16_to_f(lo[j])) * rn;
            unsigned short hh = bf16_rne(v);
            oh[j] = hh;
            ol[j] = bf16_rne(v - bf16_to_f(hh));
        }
        unsigned short* y = Y + (size_t)b * SLOT_USH + off;
        *(ushort8v*)y = oh;
        *(ushort8v*)(y + PLANE) = ol;
    }
}

// ---------------------------------------------------------------------------
// v = sign(y*s)*sqrt(|y*s|+1e-5), s = sqrt(norm[b]); pair input -> fp32 V
// ---------------------------------------------------------------------------
__device__ __forceinline__ float sgn_sqrt(float tv)
{
    float r = sqrtf(fabsf(tv) + 1e-5f);
    return tv > 0.f ? r : (tv < 0.f ? -r : 0.f);
}

__global__ __launch_bounds__(256) void ssqrt_pair(const unsigned short* __restrict__ Yf,
                                                  float* __restrict__ V,
                                                  const float* __restrict__ norm)
{
    const int total = 64 * 32768;
    for (int g = blockIdx.x * 256 + threadIdx.x; g < total; g += gridDim.x * 256) {
        const int b = g >> 15;
        const int off = (g & 32767) * 8;
        const float s = sqrtf(norm[b]);
        const unsigned short* yh = Yf + (size_t)b * SLOT_USH + off;
        ushort8v h = *(const ushort8v*)yh;
        ushort8v lo = *(const ushort8v*)(yh + PLANE);
        float* vp = V + (size_t)b * MATF + off;
        float4 o0, o1;
        o0.x = sgn_sqrt((bf16_to_f(h[0]) + bf16_to_f(lo[0])) * s);
        o0.y = sgn_sqrt((bf16_to_f(h[1]) + bf16_to_f(lo[1])) * s);
        o0.z = sgn_sqrt((bf16_to_f(h[2]) + bf16_to_f(lo[2])) * s);
        o0.w = sgn_sqrt((bf16_to_f(h[3]) + bf16_to_f(lo[3])) * s);
        o1.x = sgn_sqrt((bf16_to_f(h[4]) + bf16_to_f(lo[4])) * s);
        o1.y = sgn_sqrt((bf16_to_f(h[5]) + bf16_to_f(lo[5])) * s);
        o1.z = sgn_sqrt((bf16_to_f(h[6]) + bf16_to_f(lo[6])) * s);
        o1.w = sgn_sqrt((bf16_to_f(h[7]) + bf16_to_f(lo[7])) * s);
        *(float4*)vp = o0;
        *(float4*)(vp + 4) = o1;
    }
}

// ---------------------------------------------------------------------------
// Frobenius norm fp32 (for V)
// ---------------------------------------------------------------------------
__global__ __launch_bounds__(256) void frob_norm(const float* __restrict__ P,
                                                 float* __restrict__ out, int ob)
{
    const float* p = P + (size_t)blockIdx.x * MATF;
    float s = 0.f;
    for (int i = threadIdx.x * 4; i < DIMM * DIMM; i += 1024) {
        float4 v = *(const float4*)(p + i);
        s += v.x * v.x + v.y * v.y + v.z * v.z + v.w * v.w;
    }
    __shared__ float red[256];
    red[threadIdx.x] = s;
    __syncthreads();
    for (int wd = 128; wd > 0; wd >>= 1) {
        if (threadIdx.x < wd) red[threadIdx.x] += red[threadIdx.x + wd];
        __syncthreads();
    }
    if (threadIdx.x == 0) out[ob + blockIdx.x] = sqrtf(red[0]);
}

// ---------------------------------------------------------------------------
// FC partial GEMM (fp32, from round 1): part[sp][nt][m][n]
// ---------------------------------------------------------------------------
#define BM 64
#define BN 64
#define BK 16
__global__ __launch_bounds__(256) void fc_partial(
    const float* __restrict__ V, const float* __restrict__ Wfc, float* __restrict__ part)
{
    const int nt = blockIdx.x;
    const int sp = blockIdx.y;
    const int n0 = nt * BN;
    const size_t K = MATF;
    const int kbase = sp * 2048;

    __shared__ __align__(16) float As[BK][BM];
    __shared__ __align__(16) float Bs[BK][BN];

    const int t  = threadIdx.x;
    const int lr = t >> 2, lc = (t & 3) << 2;
    const int tx = t & 15, ty = t >> 4;

    const int wrow = n0 + lr;
    const bool wvalid = wrow < 200;
    const float* wp = Wfc + (size_t)wrow * K;

    float acc[4][4] = {};

    for (int k0 = kbase; k0 < kbase + 2048; k0 += BK) {
        float4 a4 = *(const float4*)(V + (size_t)lr * K + k0 + lc);
        float4 w4 = make_float4(0.f, 0.f, 0.f, 0.f);
        if (wvalid) w4 = *(const float4*)(wp + k0 + lc);
        As[lc + 0][lr] = a4.x; As[lc + 1][lr] = a4.y;
        As[lc + 2][lr] = a4.z; As[lc + 3][lr] = a4.w;
        Bs[lc + 0][lr] = w4.x; Bs[lc + 1][lr] = w4.y;
        Bs[lc + 2][lr] = w4.z; Bs[lc + 3][lr] = w4.w;
        __syncthreads();
#pragma unroll
        for (int kk = 0; kk < BK; ++kk) {
            float4 av = *(const float4*)&As[kk][ty << 2];
            float4 bv = *(const float4*)&Bs[kk][tx << 2];
            acc[0][0] += av.x * bv.x; acc[0][1] += av.x * bv.y; acc[0][2] += av.x * bv.z; acc[0][3] += av.x * bv.w;
            acc[1][0] += av.y * bv.x; acc[1][1] += av.y * bv.y; acc[1][2] += av.y * bv.z; acc[1][3] += av.y * bv.w;
            acc[2][0] += av.z * bv.x; acc[2][1] += av.z * bv.y; acc[2][2] += av.z * bv.z; acc[2][3] += av.z * bv.w;
            acc[3][0] += av.w * bv.x; acc[3][1] += av.w * bv.y; acc[3][2] += av.w * bv.z; acc[3][3] += av.w * bv.w;
        }
        __syncthreads();
    }

    float* pbase = part + (((size_t)sp * 4 + nt) * 64) * 64;
#pragma unroll
    for (int i = 0; i < 4; ++i) {
        const int m = (ty << 2) + i;
        float4 o;
        o.x = acc[i][0]; o.y = acc[i][1]; o.z = acc[i][2]; o.w = acc[i][3];
        *(float4*)(pbase + (size_t)m * 64 + (tx << 2)) = o;
    }
}

__global__ __launch_bounds__(256) void fc_reduce(
    const float* __restrict__ part, const float* __restrict__ n2,
    const float* __restrict__ bias, float* __restrict__ out)
{
    const int p = blockIdx.x * 256 + threadIdx.x;
    if (p >= 64 * 200) return;
    const int b = p / 200, o = p % 200;
    const int nt = o >> 6, n = o & 63;
    float s = 0.f;
    for (int c = 0; c < 128; ++c)
        s += part[(((size_t)c * 4 + nt) * 64 + b) * 64 + n];
    const float nb = fmaxf(n2[b], 1e-12f);
    out[p] = s / nb + bias[o];
}

// ---------------------------------------------------------------------------
extern "C" void kernel_launch(void* const* d_in, const int* in_sizes, int n_in,
                              void* d_out, int out_size, void* d_ws, size_t ws_size,
                              hipStream_t stream)
{
    const float* X    = (const float*)d_in[0];
    const float* Wfc  = (const float*)d_in[1];
    const float* bias = (const float*)d_in[2];
    float* out = (float*)d_out;

    float* norm  = (float*)d_ws;
    float* norm2 = norm + 64;
    float* part  = norm2 + 64;                              // 8 MiB
    unsigned short* region = (unsigned short*)(part + (size_t)128 * 4 * 64 * 64);

    unsigned short* P[4];
    for (int i = 0; i < 4; ++i) P[i] = region + (size_t)i * 64 * SLOT_USH;

    unsigned short* XHL = P[2];   // 105 MB, spans P2..P3 (dead once gram done)

    // A = X X^T / 784 (MFMA hi/lo, K padded to 800)
    xconv<<<1024, 256, 0, stream>>>(X, XHL);
    gemm_pair<0><<<dim3(16, 64, 1), 256, 0, stream>>>(
        XHL, XHL, XHL, P[0], P[0],
        KPAD, (long)XSLOT, XPLANE, KPAD, (long)XSLOT, XPLANE, KPAD, 1.0f / 784.0f);
    frob_pair<<<64, 256, 0, stream>>>(P[0], norm);
    init_pair<<<1024, 256, 0, stream>>>(P[0], P[1], norm);

    // Newton-Schulz in M-form: T(M) = (3I - M)/2 folded into epilogue
    // it0 (M0 = Y0, Z never materialized):
    //   Y1 = Y0*T(Y0) -> P2 ; M1 = Y1*T(Y0) -> P3
    gemm_pair<1><<<dim3(16, 64, 1), 256, 0, stream>>>(
        P[1], P[1], P[1], P[2], P[2],
        512, (long)SLOT_USH, PLANE, 512, (long)SLOT_USH, PLANE, 512, 1.0f);
    gemm_pair<1><<<dim3(16, 64, 1), 256, 0, stream>>>(
        P[2], P[2], P[1], P[3], P[3],
        512, (long)SLOT_USH, PLANE, 512, (long)SLOT_USH, PLANE, 512, 1.0f);

    unsigned short *Y = P[2], *M = P[3], *F0 = P[0], *F1 = P[1];
    for (int it = 1; it <= 8; ++it) {
        // s1 (merged, z=0: U = M*T(M) -> F0 ; z=1: Ynew = Y*T(M) -> F1)
        gemm_pair<1><<<dim3(16, 64, 2), 256, 0, stream>>>(
            M, Y, M, F0, F1,
            512, (long)SLOT_USH, PLANE, 512, (long)SLOT_USH, PLANE, 512, 1.0f);
        // s2: Mnew = U*T(M) -> old Y slot
        gemm_pair<1><<<dim3(16, 64, 1), 256, 0, stream>>>(
            F0, F0, M, Y, Y,
            512, (long)SLOT_USH, PLANE, 512, (long)SLOT_USH, PLANE, 512, 1.0f);
        unsigned short* Mold = M;
        M = Y;        // Mnew lives in old Y slot
        Y = F1;       // Ynew
        F1 = Mold;    // Mold freed
        // F0 (U) freed, stays as F0
    }
    // it9: YF = Y*T(M) -> F0
    gemm_pair<1><<<dim3(16, 64, 1), 256, 0, stream>>>(
        Y, Y, M, F0, F0,
        512, (long)SLOT_USH, PLANE, 512, (long)SLOT_USH, PLANE, 512, 1.0f);

    float* V = (float*)F1;   // 64 MiB fp32, distinct from F0
    ssqrt_pair<<<1024, 256, 0, stream>>>(F0, V, norm);
    frob_norm<<<64, 256, 0, stream>>>(V, norm2, 0);
    fc_partial<<<dim3(4, 128), 256, 0, stream>>>(V, Wfc, part);
    fc_reduce<<<50, 256, 0, stream>>>(part, norm2, bias, out);
}

// Round 3
// 2165.163 us; speedup vs baseline: 3.5166x; 1.4178x over previous
//
#include <hip/hip_runtime.h>
#include <math.h>
#include <stdint.h>

#define DIMM 512
#define SPAT 784
#define KPAD 800
#define MATF ((size_t)DIMM * DIMM)       // 262144
#define PLANE 262144                     // hi -> lo plane offset (ushorts) for 512x512
#define SLOT_USH (2 * 262144)            // pair slot per batch (ushorts) = 1 MiB
#define XPLANE (512 * 800)
#define XSLOT (2 * 512 * 800)

typedef __attribute__((ext_vector_type(8))) short short8v;
typedef __attribute__((ext_vector_type(8))) unsigned short ushort8v;
typedef __attribute__((ext_vector_type(4))) float f32x4;

__device__ __forceinline__ unsigned short bf16_rne(float f) {
    unsigned u = __builtin_bit_cast(unsigned, f);
    u += 0x7FFFu + ((u >> 16) & 1u);
    return (unsigned short)(u >> 16);
}
__device__ __forceinline__ float bf16_to_f(unsigned short h) {
    unsigned u = ((unsigned)h) << 16;
    return __builtin_bit_cast(float, u);
}

// ---------------------------------------------------------------------------
// Pair-plane batched GEMM:  acc = A_pair @ B_pair^T(rows-as-cols)
//   EP==0: C_pair = alpha * acc                       (Gram: B rows = X rows)
//   EP==1: C_pair = 1.5*A - 0.5*acc                   (NS: C = A @ T(M), B = M)
// hi/lo split MFMA: acc = Ah*Bh + Ah*Bl + Al*Bh  (lo*lo dropped, ~2^-18)
// 1-D grid nwg = 16 * 64 * nz (divisible by 8); XCD-aware remap so each XCD
// owns contiguous batches (L2 locality, T1). block 256 (4 waves, 2x2 of 64x64)
// ---------------------------------------------------------------------------
template<int EP>
__global__ __launch_bounds__(256) void gemm_pair(
    const unsigned short* __restrict__ A0, const unsigned short* __restrict__ A1,
    const unsigned short* __restrict__ Bb,
    unsigned short* __restrict__ C0, unsigned short* __restrict__ C1,
    int lda, long aslot, int aplane,
    int ldb, long bslot, int bplane,
    int K, float alpha, int nz)
{
    __shared__ unsigned short sm[4 * 128 * 40];   // 4 planes, rows padded to 80B
    const int SM_AH = 0, SM_AL = 5120, SM_BH = 10240, SM_BL = 15360;

    // ---- XCD-aware remap: dispatch id -> work unit, batch-contiguous per XCD
    const int nwg = gridDim.x;
    const int chunk = nwg >> 3;                   // nwg % 8 == 0 guaranteed
    const int bid = blockIdx.x;
    const int wu = (bid & 7) * chunk + (bid >> 3);
    const int per_batch = nz << 4;                // 16 tiles * nz
    const int bz = wu / per_batch;
    const int r  = wu - bz * per_batch;
    const int z  = r >> 4;
    const int tile = r & 15;

    const unsigned short* A  = (z ? A1 : A0) + (size_t)bz * aslot;
    const unsigned short* Bp = Bb + (size_t)bz * bslot;
    unsigned short* C = (z ? C1 : C0) + (size_t)bz * SLOT_USH;

    const int m0 = (tile >> 2) * 128;
    const int n0 = (tile & 3) * 128;

    const int t = threadIdx.x;
    const int l = t & 63;
    const int w = t >> 6;
    const int wr = w >> 1, wc = w & 1;
    const int lr = l & 15, lc16 = (l >> 4) * 8;   // frag read: ushort offsets

    // staging: thread covers row sr (0..127), column-half sh (16 ushorts)
    const int sr = t >> 1, sh = t & 1;
    const unsigned short* pA = A  + (size_t)(m0 + sr) * lda + sh * 16;
    const unsigned short* pB = Bp + (size_t)(n0 + sr) * ldb + sh * 16;
    unsigned short* dAh = &sm[SM_AH + sr * 40 + sh * 16];
    unsigned short* dAl = &sm[SM_AL + sr * 40 + sh * 16];
    unsigned short* dBh = &sm[SM_BH + sr * 40 + sh * 16];
    unsigned short* dBl = &sm[SM_BL + sr * 40 + sh * 16];

    f32x4 acc[4][4] = {};

    ushort8v a0, a1, a2, a3, b0, b1, b2, b3;
#define LOADALL(OFF) do { \
    a0 = *(const ushort8v*)(pA + (OFF));              a1 = *(const ushort8v*)(pA + (OFF) + 8); \
    a2 = *(const ushort8v*)(pA + aplane + (OFF));     a3 = *(const ushort8v*)(pA + aplane + (OFF) + 8); \
    b0 = *(const ushort8v*)(pB + (OFF));              b1 = *(const ushort8v*)(pB + (OFF) + 8); \
    b2 = *(const ushort8v*)(pB + bplane + (OFF));     b3 = *(const ushort8v*)(pB + bplane + (OFF) + 8); \
  } while (0)

    LOADALL(0);
    const int nsteps = K >> 5;
    for (int s = 0; s < nsteps; ++s) {
        __syncthreads();
        *(ushort8v*)(dAh) = a0; *(ushort8v*)(dAh + 8) = a1;
        *(ushort8v*)(dAl) = a2; *(ushort8v*)(dAl + 8) = a3;
        *(ushort8v*)(dBh) = b0; *(ushort8v*)(dBh + 8) = b1;
        *(ushort8v*)(dBl) = b2; *(ushort8v*)(dBl + 8) = b3;
        __syncthreads();
        if (s + 1 < nsteps) LOADALL((s + 1) * 32);

        short8v ah[4], al[4], bh[4], bl[4];
#pragma unroll
        for (int f = 0; f < 4; ++f) {
            const int ra = (wr * 64 + f * 16 + lr) * 40 + lc16;
            const int rb = (wc * 64 + f * 16 + lr) * 40 + lc16;
            ah[f] = *(const short8v*)(&sm[SM_AH + ra]);
            al[f] = *(const short8v*)(&sm[SM_AL + ra]);
            bh[f] = *(const short8v*)(&sm[SM_BH + rb]);
            bl[f] = *(const short8v*)(&sm[SM_BL + rb]);
        }
#pragma unroll
        for (int fm = 0; fm < 4; ++fm)
#pragma unroll
            for (int fn = 0; fn < 4; ++fn) {
                acc[fm][fn] = __builtin_amdgcn_mfma_f32_16x16x32_bf16(ah[fm], bh[fn], acc[fm][fn], 0, 0, 0);
                acc[fm][fn] = __builtin_amdgcn_mfma_f32_16x16x32_bf16(ah[fm], bl[fn], acc[fm][fn], 0, 0, 0);
                acc[fm][fn] = __builtin_amdgcn_mfma_f32_16x16x32_bf16(al[fm], bh[fn], acc[fm][fn], 0, 0, 0);
            }
    }
#undef LOADALL

    // epilogue: C/D layout col = lane&15, row = (lane>>4)*4 + reg  [m89-verified]
#pragma unroll
    for (int fm = 0; fm < 4; ++fm) {
#pragma unroll
        for (int j = 0; j < 4; ++j) {
            const int row = m0 + wr * 64 + fm * 16 + (l >> 4) * 4 + j;
            const unsigned short* arow = A + (size_t)row * lda;
            const size_t crow = (size_t)row * 512;
#pragma unroll
            for (int fn = 0; fn < 4; ++fn) {
                const int col = n0 + wc * 64 + fn * 16 + lr;
                float v = acc[fm][fn][j];
                if (EP == 0) {
                    v *= alpha;
                } else {
                    float pv = bf16_to_f(arow[col]) + bf16_to_f(arow[aplane + col]);
                    v = 1.5f * pv - 0.5f * v;
                }
                unsigned short hh = bf16_rne(v);
                C[crow + col] = hh;
                C[crow + col + PLANE] = bf16_rne(v - bf16_to_f(hh));
            }
        }
    }
}

// ---------------------------------------------------------------------------
// X (64,512,784) fp32 -> hi/lo bf16 planes, K padded to 800 with zeros
// ---------------------------------------------------------------------------
__global__ __launch_bounds__(256) void xconv(const float* __restrict__ X,
                                             unsigned short* __restrict__ XHL)
{
    const int total = 64 * 512 * 200;   // groups of 4 cols (padded width 800)
    for (int idx = blockIdx.x * 256 + threadIdx.x; idx < total; idx += gridDim.x * 256) {
        const int c4 = (idx % 200) * 4;
        const int rb = idx / 200;       // b*512 + r
        const int b = rb >> 9, r = rb & 511;
        unsigned short* dst = XHL + (size_t)b * XSLOT + (size_t)r * 800 + c4;
        ushort4 hv, lv;
        if (c4 < 784) {
            float4 x = *(const float4*)(X + (size_t)rb * 784 + c4);
            unsigned short h0 = bf16_rne(x.x), h1 = bf16_rne(x.y),
                           h2 = bf16_rne(x.z), h3 = bf16_rne(x.w);
            hv.x = h0; hv.y = h1; hv.z = h2; hv.w = h3;
            lv.x = bf16_rne(x.x - bf16_to_f(h0));
            lv.y = bf16_rne(x.y - bf16_to_f(h1));
            lv.z = bf16_rne(x.z - bf16_to_f(h2));
            lv.w = bf16_rne(x.w - bf16_to_f(h3));
        } else {
            hv.x = hv.y = hv.z = hv.w = 0;
            lv.x = lv.y = lv.z = lv.w = 0;
        }
        *(ushort4*)dst = hv;
        *(ushort4*)(dst + XPLANE) = lv;
    }
}

// ---------------------------------------------------------------------------
// Frobenius norm of pair-plane matrix per batch
// ---------------------------------------------------------------------------
__global__ __launch_bounds__(256) void frob_pair(const unsigned short* __restrict__ P,
                                                 float* __restrict__ out)
{
    const unsigned short* p = P + (size_t)blockIdx.x * SLOT_USH;
    float s = 0.f;
    for (int i = threadIdx.x * 8; i < 262144; i += 2048) {
        ushort8v h = *(const ushort8v*)(p + i);
        ushort8v lo = *(const ushort8v*)(p + i + PLANE);
#pragma unroll
        for (int j = 0; j < 8; ++j) {
            float v = bf16_to_f(h[j]) + bf16_to_f(lo[j]);
            s += v * v;
        }
    }
    __shared__ float red[256];
    red[threadIdx.x] = s;
    __syncthreads();
    for (int wd = 128; wd > 0; wd >>= 1) {
        if (threadIdx.x < wd) red[threadIdx.x] += red[threadIdx.x + wd];
        __syncthreads();
    }
    if (threadIdx.x == 0) out[blockIdx.x] = sqrtf(red[0]);
}

// ---------------------------------------------------------------------------
// Y0_pair = A_pair / norm[b]
// ---------------------------------------------------------------------------
__global__ __launch_bounds__(256) void init_pair(const unsigned short* __restrict__ A,
                                                 unsigned short* __restrict__ Y,
                                                 const float* __restrict__ norm)
{
    const int total = 64 * 32768;      // groups of 8
    for (int g = blockIdx.x * 256 + threadIdx.x; g < total; g += gridDim.x * 256) {
        const int b = g >> 15;
        const int off = (g & 32767) * 8;
        const float rn = 1.0f / norm[b];
        const unsigned short* ah = A + (size_t)b * SLOT_USH + off;
        ushort8v h = *(const ushort8v*)ah;
        ushort8v lo = *(const ushort8v*)(ah + PLANE);
        ushort8v oh, ol;
#pragma unroll
        for (int j = 0; j < 8; ++j) {
            float v = (bf16_to_f(h[j]) + bf16_to_f(lo[j])) * rn;
            unsigned short hh = bf16_rne(v);
            oh[j] = hh;
            ol[j] = bf16_rne(v - bf16_to_f(hh));
        }
        unsigned short* y = Y + (size_t)b * SLOT_USH + off;
        *(ushort8v*)y = oh;
        *(ushort8v*)(y + PLANE) = ol;
    }
}

// ---------------------------------------------------------------------------
// v = sign(y*s)*sqrt(|y*s|+1e-5), s = sqrt(norm[b]); pair input -> fp32 V
// ---------------------------------------------------------------------------
__device__ __forceinline__ float sgn_sqrt(float tv)
{
    float r = sqrtf(fabsf(tv) + 1e-5f);
    return tv > 0.f ? r : (tv < 0.f ? -r : 0.f);
}

__global__ __launch_bounds__(256) void ssqrt_pair(const unsigned short* __restrict__ Yf,
                                                  float* __restrict__ V,
                                                  const float* __restrict__ norm)
{
    const int total = 64 * 32768;
    for (int g = blockIdx.x * 256 + threadIdx.x; g < total; g += gridDim.x * 256) {
        const int b = g >> 15;
        const int off = (g & 32767) * 8;
        const float s = sqrtf(norm[b]);
        const unsigned short* yh = Yf + (size_t)b * SLOT_USH + off;
        ushort8v h = *(const ushort8v*)yh;
        ushort8v lo = *(const ushort8v*)(yh + PLANE);
        float* vp = V + (size_t)b * MATF + off;
        float4 o0, o1;
        o0.x = sgn_sqrt((bf16_to_f(h[0]) + bf16_to_f(lo[0])) * s);
        o0.y = sgn_sqrt((bf16_to_f(h[1]) + bf16_to_f(lo[1])) * s);
        o0.z = sgn_sqrt((bf16_to_f(h[2]) + bf16_to_f(lo[2])) * s);
        o0.w = sgn_sqrt((bf16_to_f(h[3]) + bf16_to_f(lo[3])) * s);
        o1.x = sgn_sqrt((bf16_to_f(h[4]) + bf16_to_f(lo[4])) * s);
        o1.y = sgn_sqrt((bf16_to_f(h[5]) + bf16_to_f(lo[5])) * s);
        o1.z = sgn_sqrt((bf16_to_f(h[6]) + bf16_to_f(lo[6])) * s);
        o1.w = sgn_sqrt((bf16_to_f(h[7]) + bf16_to_f(lo[7])) * s);
        *(float4*)vp = o0;
        *(float4*)(vp + 4) = o1;
    }
}

// ---------------------------------------------------------------------------
// Frobenius norm fp32 (for V)
// ---------------------------------------------------------------------------
__global__ __launch_bounds__(256) void frob_norm(const float* __restrict__ P,
                                                 float* __restrict__ out, int ob)
{
    const float* p = P + (size_t)blockIdx.x * MATF;
    float s = 0.f;
    for (int i = threadIdx.x * 4; i < DIMM * DIMM; i += 1024) {
        float4 v = *(const float4*)(p + i);
        s += v.x * v.x + v.y * v.y + v.z * v.z + v.w * v.w;
    }
    __shared__ float red[256];
    red[threadIdx.x] = s;
    __syncthreads();
    for (int wd = 128; wd > 0; wd >>= 1) {
        if (threadIdx.x < wd) red[threadIdx.x] += red[threadIdx.x + wd];
        __syncthreads();
    }
    if (threadIdx.x == 0) out[ob + blockIdx.x] = sqrtf(red[0]);
}

// ---------------------------------------------------------------------------
// FC partial GEMM (fp32): part[sp][nt][m][n]
// ---------------------------------------------------------------------------
#define BM 64
#define BN 64
#define BK 16
__global__ __launch_bounds__(256) void fc_partial(
    const float* __restrict__ V, const float* __restrict__ Wfc, float* __restrict__ part)
{
    const int nt = blockIdx.x;
    const int sp = blockIdx.y;
    const int n0 = nt * BN;
    const size_t K = MATF;
    const int kbase = sp * 2048;

    __shared__ __align__(16) float As[BK][BM];
    __shared__ __align__(16) float Bs[BK][BN];

    const int t  = threadIdx.x;
    const int lr = t >> 2, lc = (t & 3) << 2;
    const int tx = t & 15, ty = t >> 4;

    const int wrow = n0 + lr;
    const bool wvalid = wrow < 200;
    const float* wp = Wfc + (size_t)wrow * K;

    float acc[4][4] = {};

    for (int k0 = kbase; k0 < kbase + 2048; k0 += BK) {
        float4 a4 = *(const float4*)(V + (size_t)lr * K + k0 + lc);
        float4 w4 = make_float4(0.f, 0.f, 0.f, 0.f);
        if (wvalid) w4 = *(const float4*)(wp + k0 + lc);
        As[lc + 0][lr] = a4.x; As[lc + 1][lr] = a4.y;
        As[lc + 2][lr] = a4.z; As[lc + 3][lr] = a4.w;
        Bs[lc + 0][lr] = w4.x; Bs[lc + 1][lr] = w4.y;
        Bs[lc + 2][lr] = w4.z; Bs[lc + 3][lr] = w4.w;
        __syncthreads();
#pragma unroll
        for (int kk = 0; kk < BK; ++kk) {
            float4 av = *(const float4*)&As[kk][ty << 2];
            float4 bv = *(const float4*)&Bs[kk][tx << 2];
            acc[0][0] += av.x * bv.x; acc[0][1] += av.x * bv.y; acc[0][2] += av.x * bv.z; acc[0][3] += av.x * bv.w;
            acc[1][0] += av.y * bv.x; acc[1][1] += av.y * bv.y; acc[1][2] += av.y * bv.z; acc[1][3] += av.y * bv.w;
            acc[2][0] += av.z * bv.x; acc[2][1] += av.z * bv.y; acc[2][2] += av.z * bv.z; acc[2][3] += av.z * bv.w;
            acc[3][0] += av.w * bv.x; acc[3][1] += av.w * bv.y; acc[3][2] += av.w * bv.z; acc[3][3] += av.w * bv.w;
        }
        __syncthreads();
    }

    float* pbase = part + (((size_t)sp * 4 + nt) * 64) * 64;
#pragma unroll
    for (int i = 0; i < 4; ++i) {
        const int m = (ty << 2) + i;
        float4 o;
        o.x = acc[i][0]; o.y = acc[i][1]; o.z = acc[i][2]; o.w = acc[i][3];
        *(float4*)(pbase + (size_t)m * 64 + (tx << 2)) = o;
    }
}

__global__ __launch_bounds__(256) void fc_reduce(
    const float* __restrict__ part, const float* __restrict__ n2,
    const float* __restrict__ bias, float* __restrict__ out)
{
    const int p = blockIdx.x * 256 + threadIdx.x;
    if (p >= 64 * 200) return;
    const int b = p / 200, o = p % 200;
    const int nt = o >> 6, n = o & 63;
    float s = 0.f;
    for (int c = 0; c < 128; ++c)
        s += part[(((size_t)c * 4 + nt) * 64 + b) * 64 + n];
    const float nb = fmaxf(n2[b], 1e-12f);
    out[p] = s / nb + bias[o];
}

// ---------------------------------------------------------------------------
extern "C" void kernel_launch(void* const* d_in, const int* in_sizes, int n_in,
                              void* d_out, int out_size, void* d_ws, size_t ws_size,
                              hipStream_t stream)
{
    const float* X    = (const float*)d_in[0];
    const float* Wfc  = (const float*)d_in[1];
    const float* bias = (const float*)d_in[2];
    float* out = (float*)d_out;

    float* norm  = (float*)d_ws;
    float* norm2 = norm + 64;
    float* part  = norm2 + 64;                              // 8 MiB
    unsigned short* region = (unsigned short*)(part + (size_t)128 * 4 * 64 * 64);

    unsigned short* P[4];
    for (int i = 0; i < 4; ++i) P[i] = region + (size_t)i * 64 * SLOT_USH;

    unsigned short* XHL = P[2];   // 105 MB, spans P2..P3 (dead once gram done)

    // A = X X^T / 784 (MFMA hi/lo, K padded to 800)
    xconv<<<1024, 256, 0, stream>>>(X, XHL);
    gemm_pair<0><<<dim3(16 * 64), 256, 0, stream>>>(
        XHL, XHL, XHL, P[0], P[0],
        KPAD, (long)XSLOT, XPLANE, KPAD, (long)XSLOT, XPLANE, KPAD, 1.0f / 784.0f, 1);
    frob_pair<<<64, 256, 0, stream>>>(P[0], norm);
    init_pair<<<1024, 256, 0, stream>>>(P[0], P[1], norm);

    // Newton-Schulz in M-form: T(M) = (3I - M)/2 folded into epilogue
    // it0 (M0 = Y0, Z never materialized):
    //   Y1 = Y0*T(Y0) -> P2 ; M1 = Y1*T(Y0) -> P3
    gemm_pair<1><<<dim3(16 * 64), 256, 0, stream>>>(
        P[1], P[1], P[1], P[2], P[2],
        512, (long)SLOT_USH, PLANE, 512, (long)SLOT_USH, PLANE, 512, 1.0f, 1);
    gemm_pair<1><<<dim3(16 * 64), 256, 0, stream>>>(
        P[2], P[2], P[1], P[3], P[3],
        512, (long)SLOT_USH, PLANE, 512, (long)SLOT_USH, PLANE, 512, 1.0f, 1);

    unsigned short *Y = P[2], *M = P[3], *F0 = P[0], *F1 = P[1];
    for (int it = 1; it <= 8; ++it) {
        // s1 (merged, z=0: U = M*T(M) -> F0 ; z=1: Ynew = Y*T(M) -> F1)
        gemm_pair<1><<<dim3(16 * 64 * 2), 256, 0, stream>>>(
            M, Y, M, F0, F1,
            512, (long)SLOT_USH, PLANE, 512, (long)SLOT_USH, PLANE, 512, 1.0f, 2);
        // s2: Mnew = U*T(M) -> old Y slot
        gemm_pair<1><<<dim3(16 * 64), 256, 0, stream>>>(
            F0, F0, M, Y, Y,
            512, (long)SLOT_USH, PLANE, 512, (long)SLOT_USH, PLANE, 512, 1.0f, 1);
        unsigned short* Mold = M;
        M = Y;        // Mnew lives in old Y slot
        Y = F1;       // Ynew
        F1 = Mold;    // Mold freed
        // F0 (U) freed, stays as F0
    }
    // it9: YF = Y*T(M) -> F0
    gemm_pair<1><<<dim3(16 * 64), 256, 0, stream>>>(
        Y, Y, M, F0, F0,
        512, (long)SLOT_USH, PLANE, 512, (long)SLOT_USH, PLANE, 512, 1.0f, 1);

    float* V = (float*)F1;   // 64 MiB fp32, distinct from F0
    ssqrt_pair<<<1024, 256, 0, stream>>>(F0, V, norm);
    frob_norm<<<64, 256, 0, stream>>>(V, norm2, 0);
    fc_partial<<<dim3(4, 128), 256, 0, stream>>>(V, Wfc, part);
    fc_reduce<<<50, 256, 0, stream>>>(part, norm2, bias, out);
}

// Round 4
// 1730.630 us; speedup vs baseline: 4.3996x; 1.2511x over previous
//
#include <hip/hip_runtime.h>
#include <math.h>
#include <stdint.h>

#define DIMM 512
#define SPAT 784
#define KPAD 800
#define MATF ((size_t)DIMM * DIMM)       // 262144
#define PLANE 262144                     // hi -> lo plane offset (ushorts) for 512x512
#define SLOT_USH (2 * 262144)            // pair slot per batch (ushorts) = 1 MiB
#define XPLANE (512 * 800)
#define XSLOT (2 * 512 * 800)

typedef __attribute__((ext_vector_type(8))) short short8v;
typedef __attribute__((ext_vector_type(8))) unsigned short ushort8v;
typedef __attribute__((ext_vector_type(4))) float f32x4;

__device__ __forceinline__ unsigned short bf16_rne(float f) {
    unsigned u = __builtin_bit_cast(unsigned, f);
    u += 0x7FFFu + ((u >> 16) & 1u);
    return (unsigned short)(u >> 16);
}
__device__ __forceinline__ float bf16_to_f(unsigned short h) {
    unsigned u = ((unsigned)h) << 16;
    return __builtin_bit_cast(float, u);
}

// ---------------------------------------------------------------------------
// Pair-plane batched GEMM on SYMMETRIC outputs: only the 10 upper-triangle
// tiles of the 4x4 tile grid are computed; off-diagonal tiles mirror their
// result to the transposed position via an LDS transpose.
//   EP==0: C_pair = alpha * acc                       (Gram)
//   EP==1: C_pair = 1.5*A - 0.5*acc                   (NS: C = A @ T(M), B = M)
// hi/lo split MFMA: acc = Ah*Bh + Ah*Bl + Al*Bh  (lo*lo dropped, ~2^-17)
// 1-D grid nwg = 10 * 64 * nz (divisible by 8); XCD-aware remap (T1).
// block 256 (4 waves, 2x2 of 64x64)
// ---------------------------------------------------------------------------
template<int EP>
__global__ __launch_bounds__(256) void gemm_pair(
    const unsigned short* __restrict__ A0, const unsigned short* __restrict__ A1,
    const unsigned short* __restrict__ Bb,
    unsigned short* __restrict__ C0, unsigned short* __restrict__ C1,
    int lda, long aslot, int aplane,
    int ldb, long bslot, int bplane,
    int K, float alpha, int nz)
{
    __shared__ unsigned short sm[4 * 128 * 40];   // 40 KB; reused for transpose
    const int SM_AH = 0, SM_AL = 5120, SM_BH = 10240, SM_BL = 15360;

    // ---- XCD-aware remap: batch-contiguous per XCD
    const int nwg = gridDim.x;
    const int chunk = nwg >> 3;                   // nwg % 8 == 0
    const int bid = blockIdx.x;
    const int wu = (bid & 7) * chunk + (bid >> 3);
    const int per_batch = nz * 10;
    const int bz = wu / per_batch;
    const int rr = wu - bz * per_batch;
    const int z  = rr / 10;
    const int tile = rr - z * 10;
    int ti, tj;
    if (tile < 4)      { ti = 0; tj = tile; }
    else if (tile < 7) { ti = 1; tj = tile - 3; }
    else if (tile < 9) { ti = 2; tj = tile - 5; }
    else               { ti = 3; tj = 3; }

    const unsigned short* A  = (z ? A1 : A0) + (size_t)bz * aslot;
    const unsigned short* Bp = Bb + (size_t)bz * bslot;
    unsigned short* C = (z ? C1 : C0) + (size_t)bz * SLOT_USH;

    const int m0 = ti * 128;
    const int n0 = tj * 128;

    const int t = threadIdx.x;
    const int l = t & 63;
    const int w = t >> 6;
    const int wr = w >> 1, wc = w & 1;
    const int lr = l & 15, lc16 = (l >> 4) * 8;   // frag read: ushort offsets

    // staging: thread covers row sr (0..127), column-half sh (16 ushorts)
    const int sr = t >> 1, sh = t & 1;
    const unsigned short* pA = A  + (size_t)(m0 + sr) * lda + sh * 16;
    const unsigned short* pB = Bp + (size_t)(n0 + sr) * ldb + sh * 16;
    unsigned short* dAh = &sm[SM_AH + sr * 40 + sh * 16];
    unsigned short* dAl = &sm[SM_AL + sr * 40 + sh * 16];
    unsigned short* dBh = &sm[SM_BH + sr * 40 + sh * 16];
    unsigned short* dBl = &sm[SM_BL + sr * 40 + sh * 16];

    f32x4 acc[4][4] = {};

    ushort8v a0, a1, a2, a3, b0, b1, b2, b3;
#define LOADALL(OFF) do { \
    a0 = *(const ushort8v*)(pA + (OFF));              a1 = *(const ushort8v*)(pA + (OFF) + 8); \
    a2 = *(const ushort8v*)(pA + aplane + (OFF));     a3 = *(const ushort8v*)(pA + aplane + (OFF) + 8); \
    b0 = *(const ushort8v*)(pB + (OFF));              b1 = *(const ushort8v*)(pB + (OFF) + 8); \
    b2 = *(const ushort8v*)(pB + bplane + (OFF));     b3 = *(const ushort8v*)(pB + bplane + (OFF) + 8); \
  } while (0)

    LOADALL(0);
    const int nsteps = K >> 5;
    for (int s = 0; s < nsteps; ++s) {
        __syncthreads();
        *(ushort8v*)(dAh) = a0; *(ushort8v*)(dAh + 8) = a1;
        *(ushort8v*)(dAl) = a2; *(ushort8v*)(dAl + 8) = a3;
        *(ushort8v*)(dBh) = b0; *(ushort8v*)(dBh + 8) = b1;
        *(ushort8v*)(dBl) = b2; *(ushort8v*)(dBl + 8) = b3;
        __syncthreads();
        if (s + 1 < nsteps) LOADALL((s + 1) * 32);

        short8v ah[4], al[4], bh[4], bl[4];
#pragma unroll
        for (int f = 0; f < 4; ++f) {
            const int ra = (wr * 64 + f * 16 + lr) * 40 + lc16;
            const int rb = (wc * 64 + f * 16 + lr) * 40 + lc16;
            ah[f] = *(const short8v*)(&sm[SM_AH + ra]);
            al[f] = *(const short8v*)(&sm[SM_AL + ra]);
            bh[f] = *(const short8v*)(&sm[SM_BH + rb]);
            bl[f] = *(const short8v*)(&sm[SM_BL + rb]);
        }
#pragma unroll
        for (int fm = 0; fm < 4; ++fm)
#pragma unroll
            for (int fn = 0; fn < 4; ++fn) {
                acc[fm][fn] = __builtin_amdgcn_mfma_f32_16x16x32_bf16(ah[fm], bh[fn], acc[fm][fn], 0, 0, 0);
                acc[fm][fn] = __builtin_amdgcn_mfma_f32_16x16x32_bf16(ah[fm], bl[fn], acc[fm][fn], 0, 0, 0);
                acc[fm][fn] = __builtin_amdgcn_mfma_f32_16x16x32_bf16(al[fm], bh[fn], acc[fm][fn], 0, 0, 0);
            }
    }
#undef LOADALL

    // ---- epilogue: fold final value v into acc, write upper tile directly
    // C/D layout: col = lane&15, row = (lane>>4)*4 + reg  [m89-verified]
#pragma unroll
    for (int fm = 0; fm < 4; ++fm) {
#pragma unroll
        for (int j = 0; j < 4; ++j) {
            const int row = m0 + wr * 64 + fm * 16 + (l >> 4) * 4 + j;
            const unsigned short* arow = A + (size_t)row * lda;
            const size_t crow = (size_t)row * 512;
#pragma unroll
            for (int fn = 0; fn < 4; ++fn) {
                const int col = n0 + wc * 64 + fn * 16 + lr;
                float v = acc[fm][fn][j];
                if (EP == 0) {
                    v *= alpha;
                } else {
                    float pv = bf16_to_f(arow[col]) + bf16_to_f(arow[aplane + col]);
                    v = 1.5f * pv - 0.5f * v;
                }
                acc[fm][fn][j] = v;
                unsigned short hh = bf16_rne(v);
                C[crow + col] = hh;
                C[crow + col + PLANE] = bf16_rne(v - bf16_to_f(hh));
            }
        }
    }

    // ---- mirrored (lower-triangle) tile via LDS transpose, off-diagonal only
    if (ti != tj) {
        const int TP = 132;                       // pitch (ushorts), 8B-aligned rows
        unsigned short* smT = sm;                 // reuse (needs 128*132 <= 20480)
        const int cst = wc * 64 /*+ fn*16*/ + lr; // col base per lane
        const int rst = wr * 64 /*+ fm*16*/ + (l >> 4) * 4;
        const int rc = t >> 1;                    // readout row (0..127)
        const int rh = (t & 1) * 64;              // readout col half
        __syncthreads();                          // main-loop sm reads done
#pragma unroll
        for (int pl = 0; pl < 2; ++pl) {
#pragma unroll
            for (int fm = 0; fm < 4; ++fm) {
#pragma unroll
                for (int fn = 0; fn < 4; ++fn) {
                    ushort4 q;
                    {
                        float v0 = acc[fm][fn][0], v1 = acc[fm][fn][1];
                        float v2 = acc[fm][fn][2], v3 = acc[fm][fn][3];
                        unsigned short h0 = bf16_rne(v0), h1 = bf16_rne(v1);
                        unsigned short h2 = bf16_rne(v2), h3 = bf16_rne(v3);
                        if (pl == 0) { q.x = h0; q.y = h1; q.z = h2; q.w = h3; }
                        else {
                            q.x = bf16_rne(v0 - bf16_to_f(h0));
                            q.y = bf16_rne(v1 - bf16_to_f(h1));
                            q.z = bf16_rne(v2 - bf16_to_f(h2));
                            q.w = bf16_rne(v3 - bf16_to_f(h3));
                        }
                    }
                    *(ushort4*)&smT[(cst + fn * 16) * TP + rst + fm * 16] = q;
                }
            }
            __syncthreads();
            // readout: row rc of transposed tile -> C[(n0+rc)][m0 + rh .. +63]
            {
                unsigned short* dst = C + (size_t)(n0 + rc) * 512 + m0 + rh + (pl ? PLANE : 0);
                const unsigned short* srcp = &smT[rc * TP + rh];
#pragma unroll
                for (int k = 0; k < 16; ++k)
                    *(ushort4*)(dst + k * 4) = *(const ushort4*)(srcp + k * 4);
            }
            __syncthreads();
        }
    }
}

// ---------------------------------------------------------------------------
// X (64,512,784) fp32 -> hi/lo bf16 planes, K padded to 800 with zeros
// ---------------------------------------------------------------------------
__global__ __launch_bounds__(256) void xconv(const float* __restrict__ X,
                                             unsigned short* __restrict__ XHL)
{
    const int total = 64 * 512 * 200;   // groups of 4 cols (padded width 800)
    for (int idx = blockIdx.x * 256 + threadIdx.x; idx < total; idx += gridDim.x * 256) {
        const int c4 = (idx % 200) * 4;
        const int rb = idx / 200;       // b*512 + r
        const int b = rb >> 9, r = rb & 511;
        unsigned short* dst = XHL + (size_t)b * XSLOT + (size_t)r * 800 + c4;
        ushort4 hv, lv;
        if (c4 < 784) {
            float4 x = *(const float4*)(X + (size_t)rb * 784 + c4);
            unsigned short h0 = bf16_rne(x.x), h1 = bf16_rne(x.y),
                           h2 = bf16_rne(x.z), h3 = bf16_rne(x.w);
            hv.x = h0; hv.y = h1; hv.z = h2; hv.w = h3;
            lv.x = bf16_rne(x.x - bf16_to_f(h0));
            lv.y = bf16_rne(x.y - bf16_to_f(h1));
            lv.z = bf16_rne(x.z - bf16_to_f(h2));
            lv.w = bf16_rne(x.w - bf16_to_f(h3));
        } else {
            hv.x = hv.y = hv.z = hv.w = 0;
            lv.x = lv.y = lv.z = lv.w = 0;
        }
        *(ushort4*)dst = hv;
        *(ushort4*)(dst + XPLANE) = lv;
    }
}

// ---------------------------------------------------------------------------
// Frobenius norm of pair-plane matrix per batch (slot stride SLOT_USH)
// ---------------------------------------------------------------------------
__global__ __launch_bounds__(256) void frob_pair(const unsigned short* __restrict__ P,
                                                 float* __restrict__ out)
{
    const unsigned short* p = P + (size_t)blockIdx.x * SLOT_USH;
    float s = 0.f;
    for (int i = threadIdx.x * 8; i < 262144; i += 2048) {
        ushort8v h = *(const ushort8v*)(p + i);
        ushort8v lo = *(const ushort8v*)(p + i + PLANE);
#pragma unroll
        for (int j = 0; j < 8; ++j) {
            float v = bf16_to_f(h[j]) + bf16_to_f(lo[j]);
            s += v * v;
        }
    }
    __shared__ float red[256];
    red[threadIdx.x] = s;
    __syncthreads();
    for (int wd = 128; wd > 0; wd >>= 1) {
        if (threadIdx.x < wd) red[threadIdx.x] += red[threadIdx.x + wd];
        __syncthreads();
    }
    if (threadIdx.x == 0) out[blockIdx.x] = sqrtf(red[0]);
}

// ---------------------------------------------------------------------------
// Y0_pair = A_pair / norm[b]
// ---------------------------------------------------------------------------
__global__ __launch_bounds__(256) void init_pair(const unsigned short* __restrict__ A,
                                                 unsigned short* __restrict__ Y,
                                                 const float* __restrict__ norm)
{
    const int total = 64 * 32768;      // groups of 8
    for (int g = blockIdx.x * 256 + threadIdx.x; g < total; g += gridDim.x * 256) {
        const int b = g >> 15;
        const int off = (g & 32767) * 8;
        const float rn = 1.0f / norm[b];
        const unsigned short* ah = A + (size_t)b * SLOT_USH + off;
        ushort8v h = *(const ushort8v*)ah;
        ushort8v lo = *(const ushort8v*)(ah + PLANE);
        ushort8v oh, ol;
#pragma unroll
        for (int j = 0; j < 8; ++j) {
            float v = (bf16_to_f(h[j]) + bf16_to_f(lo[j])) * rn;
            unsigned short hh = bf16_rne(v);
            oh[j] = hh;
            ol[j] = bf16_rne(v - bf16_to_f(hh));
        }
        unsigned short* y = Y + (size_t)b * SLOT_USH + off;
        *(ushort8v*)y = oh;
        *(ushort8v*)(y + PLANE) = ol;
    }
}

// ---------------------------------------------------------------------------
// v = sign(y*s)*sqrt(|y*s|+1e-5), s = sqrt(norm[b]); pair in -> pair out (V)
// ---------------------------------------------------------------------------
__device__ __forceinline__ float sgn_sqrt(float tv)
{
    float r = sqrtf(fabsf(tv) + 1e-5f);
    return tv > 0.f ? r : (tv < 0.f ? -r : 0.f);
}

__global__ __launch_bounds__(256) void ssqrt_pair(const unsigned short* __restrict__ Yf,
                                                  unsigned short* __restrict__ Vp,
                                                  const float* __restrict__ norm)
{
    const int total = 64 * 32768;
    for (int g = blockIdx.x * 256 + threadIdx.x; g < total; g += gridDim.x * 256) {
        const int b = g >> 15;
        const int off = (g & 32767) * 8;
        const float s = sqrtf(norm[b]);
        const unsigned short* yh = Yf + (size_t)b * SLOT_USH + off;
        ushort8v h = *(const ushort8v*)yh;
        ushort8v lo = *(const ushort8v*)(yh + PLANE);
        ushort8v oh, ol;
#pragma unroll
        for (int j = 0; j < 8; ++j) {
            float v = sgn_sqrt((bf16_to_f(h[j]) + bf16_to_f(lo[j])) * s);
            unsigned short hh = bf16_rne(v);
            oh[j] = hh;
            ol[j] = bf16_rne(v - bf16_to_f(hh));
        }
        unsigned short* vp = Vp + (size_t)b * SLOT_USH + off;
        *(ushort8v*)vp = oh;
        *(ushort8v*)(vp + PLANE) = ol;
    }
}

// ---------------------------------------------------------------------------
// FC via MFMA, k-split: grid = 128 sp x 2 nt. Per block: 64x128 output tile
// for K-chunk 2048. A = V pair (bf16 hi/lo, per-batch slots); B = W fp32
// converted to trunc-hi/lo in-register at staging. Partials fp32.
// ---------------------------------------------------------------------------
__global__ __launch_bounds__(256) void fc_mfma(
    const unsigned short* __restrict__ Vp, const float* __restrict__ Wfc,
    float* __restrict__ part)
{
    __shared__ unsigned short sm2[15360];   // AH 64x40, AL 64x40, BH 128x40, BL 128x40
    const int AH = 0, AL = 2560, BH = 5120, BL = 10240;

    const int sp = blockIdx.x >> 1;
    const int nt = blockIdx.x & 1;
    const int kbase = sp * 2048;
    const int n0 = nt * 128;

    const int t = threadIdx.x;
    const int l = t & 63;
    const int w = t >> 6;
    const int wr = w >> 1, wc = w & 1;
    const int lr = l & 15, lc16 = (l >> 4) * 8;

    const int sr = t >> 1, sh = t & 1;       // staging row / col-half
    const unsigned short* gA = Vp + (size_t)sr * SLOT_USH + kbase + sh * 16;  // t<128
    const int wrow = n0 + sr;
    const bool wv = wrow < 200;
    const float* gB = Wfc + (size_t)wrow * 262144 + kbase + sh * 16;

    unsigned short* dAh = &sm2[AH + sr * 40 + sh * 16];
    unsigned short* dAl = &sm2[AL + sr * 40 + sh * 16];
    unsigned short* dBh = &sm2[BH + sr * 40 + sh * 16];
    unsigned short* dBl = &sm2[BL + sr * 40 + sh * 16];

    f32x4 acc[2][4] = {};

    ushort8v va0, va1, vl0, vl1;
    float4 wf0, wf1, wf2, wf3;
#define FLOAD(OFF) do { \
    if (t < 128) { \
        va0 = *(const ushort8v*)(gA + (OFF));         va1 = *(const ushort8v*)(gA + (OFF) + 8); \
        vl0 = *(const ushort8v*)(gA + PLANE + (OFF)); vl1 = *(const ushort8v*)(gA + PLANE + (OFF) + 8); \
    } \
    if (wv) { \
        wf0 = *(const float4*)(gB + (OFF));      wf1 = *(const float4*)(gB + (OFF) + 4); \
        wf2 = *(const float4*)(gB + (OFF) + 8);  wf3 = *(const float4*)(gB + (OFF) + 12); \
    } else { \
        wf0 = wf1 = wf2 = wf3 = make_float4(0.f, 0.f, 0.f, 0.f); \
    } \
  } while (0)

#define WCONV(F4, Q) do { \
    ushort4 h4, l4; \
    unsigned ux = __builtin_bit_cast(unsigned, (F4).x); \
    unsigned uy = __builtin_bit_cast(unsigned, (F4).y); \
    unsigned uz = __builtin_bit_cast(unsigned, (F4).z); \
    unsigned uw = __builtin_bit_cast(unsigned, (F4).w); \
    h4.x = (unsigned short)(ux >> 16); h4.y = (unsigned short)(uy >> 16); \
    h4.z = (unsigned short)(uz >> 16); h4.w = (unsigned short)(uw >> 16); \
    l4.x = (unsigned short)(__builtin_bit_cast(unsigned, (F4).x - __builtin_bit_cast(float, ux & 0xFFFF0000u)) >> 16); \
    l4.y = (unsigned short)(__builtin_bit_cast(unsigned, (F4).y - __builtin_bit_cast(float, uy & 0xFFFF0000u)) >> 16); \
    l4.z = (unsigned short)(__builtin_bit_cast(unsigned, (F4).z - __builtin_bit_cast(float, uz & 0xFFFF0000u)) >> 16); \
    l4.w = (unsigned short)(__builtin_bit_cast(unsigned, (F4).w - __builtin_bit_cast(float, uw & 0xFFFF0000u)) >> 16); \
    *(ushort4*)(dBh + (Q) * 4) = h4; \
    *(ushort4*)(dBl + (Q) * 4) = l4; \
  } while (0)

    FLOAD(0);
    for (int s = 0; s < 64; ++s) {
        __syncthreads();
        if (t < 128) {
            *(ushort8v*)(dAh) = va0; *(ushort8v*)(dAh + 8) = va1;
            *(ushort8v*)(dAl) = vl0; *(ushort8v*)(dAl + 8) = vl1;
        }
        WCONV(wf0, 0); WCONV(wf1, 1); WCONV(wf2, 2); WCONV(wf3, 3);
        __syncthreads();
        if (s + 1 < 64) FLOAD((s + 1) * 32);

        short8v ah[2], al2[2], bh[4], bl[4];
#pragma unroll
        for (int f = 0; f < 2; ++f) {
            const int ra = (wr * 32 + f * 16 + lr) * 40 + lc16;
            ah[f]  = *(const short8v*)(&sm2[AH + ra]);
            al2[f] = *(const short8v*)(&sm2[AL + ra]);
        }
#pragma unroll
        for (int f = 0; f < 4; ++f) {
            const int rb = (wc * 64 + f * 16 + lr) * 40 + lc16;
            bh[f] = *(const short8v*)(&sm2[BH + rb]);
            bl[f] = *(const short8v*)(&sm2[BL + rb]);
        }
#pragma unroll
        for (int fm = 0; fm < 2; ++fm)
#pragma unroll
            for (int fn = 0; fn < 4; ++fn) {
                acc[fm][fn] = __builtin_amdgcn_mfma_f32_16x16x32_bf16(ah[fm],  bh[fn], acc[fm][fn], 0, 0, 0);
                acc[fm][fn] = __builtin_amdgcn_mfma_f32_16x16x32_bf16(ah[fm],  bl[fn], acc[fm][fn], 0, 0, 0);
                acc[fm][fn] = __builtin_amdgcn_mfma_f32_16x16x32_bf16(al2[fm], bh[fn], acc[fm][fn], 0, 0, 0);
            }
    }
#undef FLOAD
#undef WCONV

    float* pb = part + (size_t)(sp * 2 + nt) * 64 * 128;
#pragma unroll
    for (int fm = 0; fm < 2; ++fm)
#pragma unroll
        for (int j = 0; j < 4; ++j) {
            const int row = wr * 32 + fm * 16 + (l >> 4) * 4 + j;
#pragma unroll
            for (int fn = 0; fn < 4; ++fn) {
                const int col = wc * 64 + fn * 16 + lr;
                pb[(size_t)row * 128 + col] = acc[fm][fn][j];
            }
        }
}

// ---------------------------------------------------------------------------
// Final reduce: out[b][o] = (sum_sp part[sp][o>>7][b][o&127]) / max(n2,eps) + bias
// ---------------------------------------------------------------------------
__global__ __launch_bounds__(256) void fc_reduce(
    const float* __restrict__ part, const float* __restrict__ n2,
    const float* __restrict__ bias, float* __restrict__ out)
{
    const int p = blockIdx.x * 256 + threadIdx.x;
    if (p >= 64 * 200) return;
    const int b = p / 200, o = p % 200;
    const int nt = o >> 7, n = o & 127;
    float s = 0.f;
    for (int c = 0; c < 128; ++c)
        s += part[((size_t)(c * 2 + nt) * 64 + b) * 128 + n];
    const float nb = fmaxf(n2[b], 1e-12f);
    out[p] = s / nb + bias[o];
}

// ---------------------------------------------------------------------------
extern "C" void kernel_launch(void* const* d_in, const int* in_sizes, int n_in,
                              void* d_out, int out_size, void* d_ws, size_t ws_size,
                              hipStream_t stream)
{
    const float* X    = (const float*)d_in[0];
    const float* Wfc  = (const float*)d_in[1];
    const float* bias = (const float*)d_in[2];
    float* out = (float*)d_out;

    float* norm  = (float*)d_ws;
    float* norm2 = norm + 64;
    float* part  = norm2 + 64;                              // 8 MiB (256*64*128 f32)
    unsigned short* region = (unsigned short*)(part + (size_t)256 * 64 * 128);

    unsigned short* P[4];
    for (int i = 0; i < 4; ++i) P[i] = region + (size_t)i * 64 * SLOT_USH;

    unsigned short* XHL = P[2];   // 105 MB, spans P2..P3 (dead once gram done)

    // A = X X^T / 784 (MFMA hi/lo, K padded to 800), symmetric 10-tile
    xconv<<<1024, 256, 0, stream>>>(X, XHL);
    gemm_pair<0><<<dim3(10 * 64), 256, 0, stream>>>(
        XHL, XHL, XHL, P[0], P[0],
        KPAD, (long)XSLOT, XPLANE, KPAD, (long)XSLOT, XPLANE, KPAD, 1.0f / 784.0f, 1);
    frob_pair<<<64, 256, 0, stream>>>(P[0], norm);
    init_pair<<<1024, 256, 0, stream>>>(P[0], P[1], norm);

    // Newton-Schulz in M-form: T(M) = (3I - M)/2 folded into epilogue
    // it0 (M0 = Y0):  Y1 = Y0*T(Y0) -> P2 ; M1 = Y1*T(Y0) -> P3
    gemm_pair<1><<<dim3(10 * 64), 256, 0, stream>>>(
        P[1], P[1], P[1], P[2], P[2],
        512, (long)SLOT_USH, PLANE, 512, (long)SLOT_USH, PLANE, 512, 1.0f, 1);
    gemm_pair<1><<<dim3(10 * 64), 256, 0, stream>>>(
        P[2], P[2], P[1], P[3], P[3],
        512, (long)SLOT_USH, PLANE, 512, (long)SLOT_USH, PLANE, 512, 1.0f, 1);

    unsigned short *Y = P[2], *M = P[3], *F0 = P[0], *F1 = P[1];
    for (int it = 1; it <= 8; ++it) {
        // s1 merged: z=0: U = M*T(M) -> F0 ; z=1: Ynew = Y*T(M) -> F1
        gemm_pair<1><<<dim3(10 * 64 * 2), 256, 0, stream>>>(
            M, Y, M, F0, F1,
            512, (long)SLOT_USH, PLANE, 512, (long)SLOT_USH, PLANE, 512, 1.0f, 2);
        // s2: Mnew = U*T(M) -> old Y slot
        gemm_pair<1><<<dim3(10 * 64), 256, 0, stream>>>(
            F0, F0, M, Y, Y,
            512, (long)SLOT_USH, PLANE, 512, (long)SLOT_USH, PLANE, 512, 1.0f, 1);
        unsigned short* Mold = M;
        M = Y;        // Mnew lives in old Y slot
        Y = F1;       // Ynew
        F1 = Mold;    // Mold freed
    }
    // it9: YF = Y*T(M) -> F0
    gemm_pair<1><<<dim3(10 * 64), 256, 0, stream>>>(
        Y, Y, M, F0, F0,
        512, (long)SLOT_USH, PLANE, 512, (long)SLOT_USH, PLANE, 512, 1.0f, 1);

    // v = signed-sqrt (pair), n2 = ||v||, FC head via MFMA k-split
    unsigned short* Vp = F1;
    ssqrt_pair<<<1024, 256, 0, stream>>>(F0, Vp, norm);
    frob_pair<<<64, 256, 0, stream>>>(Vp, norm2);
    fc_mfma<<<dim3(256), 256, 0, stream>>>(Vp, Wfc, part);
    fc_reduce<<<50, 256, 0, stream>>>(part, norm2, bias, out);
}